// Round 5
// baseline (336.610 us; speedup 1.0000x reference)
//
#include <hip/hip_runtime.h>
#include <hip/hip_cooperative_groups.h>

// out[m,k] = D*(w-1)*rowsum(t[m]) broadcast over k (K = D = 2048).
//
// Evidence ledger (kernel-side = harness - ~160us fills, +-4 noise):
//  R0  fused 4-row NT/NT:                ~61 us
//  R9  two kernels, pure streams NT/NT:  ~59 us (best)
//  R10 one kernel phased NT/NT:          ~63 us
//  R11 cached loads (one flip):          80.6 us direct — cached reads LOSE
//      (50% L3 hit yet slower; hit/miss-mix path worse than pure NT miss)
//  R12 cached stores (one flip):         ~64 us — store policy is a wash
// Landscape flat at ~60+-3 across structure/depth/policy/grid. R9's edge:
// DEVICE-WIDE stream purity via hard kernel boundary; it pays a launch gap
// + 64KB rs HBM round-trip. R10's edge: no gap; but purity only approximate
// (no cross-block sync, 2 block generations).
//
// R13: combine both — ONE cooperative kernel, grid.sync() as the phase
// boundary. Exact device-wide read purity, then exact write purity; zero
// gap; sums persist in registers across the sync. 1024 blocks x 256 = 4096
// waves x 4 rows; ~60 VGPR (measured R11/R12 for this buffer structure)
// => co-resides at 4 blocks/CU with 2x margin. Read: 2-row double-buffered
// NT (16 KB in flight/wave, 16 waves/CU). Write: pure NT stream.
// Predict: FETCH~=WRITE~=131072 KB; if purity is the lever, kernel ~48-52,
// harness ~206-212. If flat again (~219-224): 14th flat point => practical
// mixed-stream floor reached (AMD's copyBuffer does these bytes in 79 us;
// we are at ~60) — declare roofline.

namespace cg = cooperative_groups;

#define M_ROWS 16384
#define D_COLS 2048
#define F4_PER_ROW (D_COLS / 4)   // 512
#define WAVES_PER_BLOCK 4
#define BLOCK_SIZE (WAVES_PER_BLOCK * 64)
#define ROWS_PER_WAVE 4
#define GRID_BLOCKS (M_ROWS / (WAVES_PER_BLOCK * ROWS_PER_WAVE))  // 1024

typedef float vf4 __attribute__((ext_vector_type(4)));

__global__ __launch_bounds__(BLOCK_SIZE, 4)   // cap VGPR at 128: >=4 blocks/CU
void perm_equiv_coop(const float* __restrict__ t,
                     const float* __restrict__ w,
                     float* __restrict__ out) {
    const int lane  = threadIdx.x & 63;
    const int gwave = blockIdx.x * WAVES_PER_BLOCK + (threadIdx.x >> 6);
    const size_t row0 = (size_t)gwave * ROWS_PER_WAVE;   // 4 contiguous rows

    const float scale = (float)D_COLS * (w[0] - 1.0f);

    const vf4* base = reinterpret_cast<const vf4*>(t) + row0 * F4_PER_ROW;

    vf4 buf0[8], buf1[8];          // 2-row double buffer (~60 VGPR total)
    float sums[ROWS_PER_WAVE];

    // ---- device-wide pure READ phase ----
    #pragma unroll
    for (int j = 0; j < 8; ++j)
        buf0[j] = __builtin_nontemporal_load(base + j * 64 + lane);

    #pragma unroll
    for (int r = 0; r < ROWS_PER_WAVE; ++r) {
        if (r + 1 < ROWS_PER_WAVE) {
            const vf4* p = base + (size_t)(r + 1) * F4_PER_ROW;
            if (r & 1) {
                #pragma unroll
                for (int j = 0; j < 8; ++j)
                    buf0[j] = __builtin_nontemporal_load(p + j * 64 + lane);
            } else {
                #pragma unroll
                for (int j = 0; j < 8; ++j)
                    buf1[j] = __builtin_nontemporal_load(p + j * 64 + lane);
            }
        }

        float s = 0.0f;
        if (r & 1) {
            #pragma unroll
            for (int j = 0; j < 8; ++j)
                s += (buf1[j].x + buf1[j].y) + (buf1[j].z + buf1[j].w);
        } else {
            #pragma unroll
            for (int j = 0; j < 8; ++j)
                s += (buf0[j].x + buf0[j].y) + (buf0[j].z + buf0[j].w);
        }

        // wave-64 butterfly: every lane ends with the full row sum.
        #pragma unroll
        for (int m = 32; m > 0; m >>= 1)
            s += __shfl_xor(s, m, 64);

        sums[r] = scale * s;
    }

    // ---- exact device-wide phase boundary (sums live in registers) ----
    cg::this_grid().sync();

    // ---- device-wide pure WRITE phase ----
    vf4* obase = reinterpret_cast<vf4*>(out) + row0 * F4_PER_ROW;
    #pragma unroll
    for (int r = 0; r < ROWS_PER_WAVE; ++r) {
        vf4 v4;
        v4.x = sums[r]; v4.y = sums[r]; v4.z = sums[r]; v4.w = sums[r];
        vf4* orow = obase + (size_t)r * F4_PER_ROW;
        #pragma unroll
        for (int j = 0; j < 8; ++j)
            __builtin_nontemporal_store(v4, orow + j * 64 + lane);
    }
}

extern "C" void kernel_launch(void* const* d_in, const int* in_sizes, int n_in,
                              void* d_out, int out_size, void* d_ws, size_t ws_size,
                              hipStream_t stream) {
    const float* t = (const float*)d_in[0];
    const float* w = (const float*)d_in[1];
    float* out = (float*)d_out;

    void* args[] = { (void*)&t, (void*)&w, (void*)&out };
    hipLaunchCooperativeKernel((const void*)perm_equiv_coop,
                               dim3(GRID_BLOCKS), dim3(BLOCK_SIZE),
                               args, 0, stream);
}

// Round 7
// 220.376 us; speedup vs baseline: 1.5274x; 1.5274x over previous
//
#include <hip/hip_runtime.h>

// out[m,k] = D*(w-1)*rowsum(t[m]) broadcast over k (K = D = 2048).
//
// Evidence ledger (kernel-side = harness - ~160us fills, +-4 noise):
//  R0  fused 4-row deep NT/NT:           ~61 us
//  R9  split (weak 1-row read kernel):   ~59 us (best harness 219.3)
//  R10 one-kernel phased NT/NT:          ~63 us
//  R11 cached loads:                     80.6 us direct (rejected)
//  R12 cached stores:                    ~64 us (wash)
//  R13 cooperative grid.sync:            152 us direct (VGPR crushed to 32,
//      loads sank into consume loop — no pipeline; cooperative REJECTED)
//  R14 (this kernel): NO DATA — container failed twice (infra, not kernel).
//      Resubmitting unchanged to preserve the A/B.
// R13 counters' gift: FETCH = 65.6 MB = HALF the input, even with NT loads
// (same for R11 and for AMD's copyBuffer). Mem-side cache serves 67 MB/iter
// regardless of policy => real HBM traffic is ~201 MB/iter; at ~60 us thats
// 3.35 TB/s — only half the fill-proven 6.7 TB/s. Floor is NOT the bus yet.
//
// R14/R15: the one untested cell — R9's SPLIT structure x R0's DEEP read
// pipeline. Kernel A: 4 rows/wave, ALL 32 NT dwordx4 issued before any
// consumption (32 KB in flight/wave, 1024 blocks => 16 waves/CU => up to
// 512 KB/CU outstanding), butterfly per row, lane-0 PLAIN store of
// scale*rowsum to 64 KB rs (stays cached for B). Kernel B: fill-shaped
// pure NT-store stream, one uniform rs read per wave.
// Predict: A ~18-22, B ~20-22, gap ~3-6 => harness ~203-210. If >=216:
// every axis exhausted at the same wall => declare roofline.

#define M_ROWS 16384
#define D_COLS 2048
#define F4_PER_ROW (D_COLS / 4)   // 512
#define WAVES_PER_BLOCK 4
#define BLOCK_SIZE (WAVES_PER_BLOCK * 64)

#define A_ROWS_PER_WAVE 4
#define A_GRID (M_ROWS / (WAVES_PER_BLOCK * A_ROWS_PER_WAVE))  // 1024

#define B_GRID (M_ROWS / WAVES_PER_BLOCK)                      // 4096

typedef float vf4 __attribute__((ext_vector_type(4)));

__global__ __launch_bounds__(BLOCK_SIZE)
void rowsum_deep(const float* __restrict__ t,
                 const float* __restrict__ w,
                 float* __restrict__ rs) {
    const int lane  = threadIdx.x & 63;
    const int gwave = blockIdx.x * WAVES_PER_BLOCK + (threadIdx.x >> 6);
    const size_t row0 = (size_t)gwave * A_ROWS_PER_WAVE;  // 4 contiguous rows

    const float scale = (float)D_COLS * (w[0] - 1.0f);

    const vf4* base = reinterpret_cast<const vf4*>(t) + row0 * F4_PER_ROW;

    // R0's proven read engine: all 32 NT loads in flight before consuming.
    vf4 v[A_ROWS_PER_WAVE][8];
    #pragma unroll
    for (int r = 0; r < A_ROWS_PER_WAVE; ++r) {
        const vf4* p = base + (size_t)r * F4_PER_ROW;
        #pragma unroll
        for (int j = 0; j < 8; ++j)
            v[r][j] = __builtin_nontemporal_load(p + j * 64 + lane);
    }

    // Consume in issue order: compiler emits a descending vmcnt ladder
    // (24/16/8/0) so later rows' loads stay in flight during reduction.
    #pragma unroll
    for (int r = 0; r < A_ROWS_PER_WAVE; ++r) {
        float s = 0.0f;
        #pragma unroll
        for (int j = 0; j < 8; ++j)
            s += (v[r][j].x + v[r][j].y) + (v[r][j].z + v[r][j].w);

        #pragma unroll
        for (int m = 32; m > 0; m >>= 1)
            s += __shfl_xor(s, m, 64);

        if (lane == 0)
            rs[row0 + r] = scale * s;   // plain store: keep rs in L2 for B
    }
}

__global__ __launch_bounds__(BLOCK_SIZE)
void bcast_fill(const float* __restrict__ rs,
                float* __restrict__ out) {
    const int lane = threadIdx.x & 63;
    const int row  = blockIdx.x * WAVES_PER_BLOCK + (threadIdx.x >> 6);

    const float val = rs[row];          // uniform per wave, L2-warm
    vf4 v4;
    v4.x = val; v4.y = val; v4.z = val; v4.w = val;

    vf4* orow = reinterpret_cast<vf4*>(out) + (size_t)row * F4_PER_ROW;
    #pragma unroll
    for (int j = 0; j < 8; ++j)
        __builtin_nontemporal_store(v4, orow + j * 64 + lane);
}

extern "C" void kernel_launch(void* const* d_in, const int* in_sizes, int n_in,
                              void* d_out, int out_size, void* d_ws, size_t ws_size,
                              hipStream_t stream) {
    const float* t = (const float*)d_in[0];
    const float* w = (const float*)d_in[1];
    float* out = (float*)d_out;
    float* rs  = (float*)d_ws;   // 16384 floats = 64 KB scratch

    rowsum_deep<<<A_GRID, BLOCK_SIZE, 0, stream>>>(t, w, rs);
    bcast_fill<<<B_GRID, BLOCK_SIZE, 0, stream>>>(rs, out);
}